// Round 1
// baseline (197.934 us; speedup 1.0000x reference)
//
#include <hip/hip_runtime.h>
#include <math.h>

#define NCLASS 1000
#define NCHUNK 250            // 1000 / 4 float4 chunks per row
#define ROWS_PER_WAVE 4
#define WAVES_PER_BLOCK 4
#define ROWS_PER_BLOCK (ROWS_PER_WAVE * WAVES_PER_BLOCK)

// Per block: (a) max over a slice of distance_matrix, (b) 16 rows of
// fused max/argmax + logsumexp + gather, partials to ws (no atomics).
__global__ __launch_bounds__(256) void hce_main(
    const float* __restrict__ y_pred,
    const int*   __restrict__ y_true,
    const float* __restrict__ D,
    float* __restrict__ partial,   // [0,nb): sums; [nb,2nb): D-slice maxes
    int nb, int dsize)
{
    const int tid  = threadIdx.x;
    const int lane = tid & 63;
    const int wave = tid >> 6;
    const int b    = blockIdx.x;

    // ---- part 1: distance_matrix max over this block's slice ----
    float dm = -1.0f;                      // D is uniform[0,1): nonnegative
    for (int i = b * 256 + tid; i < dsize; i += nb * 256)
        dm = fmaxf(dm, D[i]);
    #pragma unroll
    for (int off = 32; off; off >>= 1)
        dm = fmaxf(dm, __shfl_xor(dm, off, 64));

    __shared__ float smax[WAVES_PER_BLOCK];
    __shared__ float ssum[WAVES_PER_BLOCK];
    if (lane == 0) smax[wave] = dm;

    // ---- part 2: 4 rows per wave ----
    float acc = 0.0f;
    const int row0 = b * ROWS_PER_BLOCK + wave * ROWS_PER_WAVE;
    for (int r = 0; r < ROWS_PER_WAVE; ++r) {
        const int row = row0 + r;
        const float4* rp4 = (const float4*)(y_pred + (size_t)row * NCLASS);

        float4 v[4];
        #pragma unroll
        for (int t = 0; t < 4; ++t) {
            int c = lane + 64 * t;
            if (c < NCHUNK) v[t] = rp4[c];
        }
        const int nt = (lane + 192 < NCHUNK) ? 4 : 3;

        // phase 1: max + argmax (first occurrence == min col among ties)
        float m = -INFINITY; int arg = 0;
        #pragma unroll
        for (int t = 0; t < 4; ++t) {
            if (t < nt) {
                int col = 4 * (lane + 64 * t);
                if (v[t].x > m) { m = v[t].x; arg = col;     }
                if (v[t].y > m) { m = v[t].y; arg = col + 1; }
                if (v[t].z > m) { m = v[t].z; arg = col + 2; }
                if (v[t].w > m) { m = v[t].w; arg = col + 3; }
            }
        }
        #pragma unroll
        for (int off = 32; off; off >>= 1) {
            float om = __shfl_xor(m,   off, 64);
            int   oa = __shfl_xor(arg, off, 64);
            if (om > m || (om == m && oa < arg)) { m = om; arg = oa; }
        }

        // phase 2: sum of exp(x - m)
        float s = 0.0f;
        #pragma unroll
        for (int t = 0; t < 4; ++t) {
            if (t < nt) {
                s += __expf(v[t].x - m) + __expf(v[t].y - m)
                   + __expf(v[t].z - m) + __expf(v[t].w - m);
            }
        }
        #pragma unroll
        for (int off = 32; off; off >>= 1)
            s += __shfl_xor(s, off, 64);

        if (lane == 0) {
            int   tgt  = y_true[row];
            float xt   = y_pred[(size_t)row * NCLASS + tgt];
            float logp = xt - m - __logf(s);
            float d    = D[arg * NCLASS + tgt];
            acc += logp * d;
        }
    }

    if (lane == 0) ssum[wave] = acc;
    __syncthreads();
    if (tid == 0) {
        partial[b]      = ssum[0] + ssum[1] + ssum[2] + ssum[3];
        partial[nb + b] = fmaxf(fmaxf(smax[0], smax[1]),
                                fmaxf(smax[2], smax[3]));
    }
}

__global__ __launch_bounds__(256) void hce_finalize(
    const float* __restrict__ partial, int nb,
    float* __restrict__ out, float invB)
{
    const int tid  = threadIdx.x;
    const int lane = tid & 63;
    const int wave = tid >> 6;
    float s = 0.0f, mx = -1.0f;
    for (int i = tid; i < nb; i += 256) {
        s  += partial[i];
        mx  = fmaxf(mx, partial[nb + i]);
    }
    #pragma unroll
    for (int off = 32; off; off >>= 1) {
        s  += __shfl_xor(s, off, 64);
        mx  = fmaxf(mx, __shfl_xor(mx, off, 64));
    }
    __shared__ float ss[4], sm[4];
    if (lane == 0) { ss[wave] = s; sm[wave] = mx; }
    __syncthreads();
    if (tid == 0) {
        float S = ss[0] + ss[1] + ss[2] + ss[3];
        float M = fmaxf(fmaxf(sm[0], sm[1]), fmaxf(sm[2], sm[3]));
        out[0] = -S * invB / M;
    }
}

extern "C" void kernel_launch(void* const* d_in, const int* in_sizes, int n_in,
                              void* d_out, int out_size, void* d_ws, size_t ws_size,
                              hipStream_t stream) {
    const float* y_pred = (const float*)d_in[0];
    const int*   y_true = (const int*)  d_in[1];
    const float* D      = (const float*)d_in[2];
    // d_in[3] (fix_layer) is dead code in the reference.
    float* out = (float*)d_out;
    float* ws  = (float*)d_ws;

    const int B     = in_sizes[1];          // 32768
    const int dsize = in_sizes[2];          // 1000*1000
    const int nb    = B / ROWS_PER_BLOCK;   // 2048 blocks

    hce_main<<<nb, 256, 0, stream>>>(y_pred, y_true, D, ws, nb, dsize);
    hce_finalize<<<1, 256, 0, stream>>>(ws, nb, out, 1.0f / (float)B);
}